// Round 6
// baseline (236.195 us; speedup 1.0000x reference)
//
#include <hip/hip_runtime.h>
#include <math.h>

#define LVL 16
#define TBL 65536
#define BATCH 8
#define NPIX 65536       // 256*256
#define SDIM 512
#define HPRIME 2654435761u

struct ResPack { int r[LVL]; };

// ---------------------------------------------------------------------------
// Kernel A (round-1 verified, unchanged): fp32 modulated weights.
// weff per b (stride 2144 floats): [0,1024) W0 [32][32] (o,i), [1024,2048) W1,
// [2048,2144) W2 [3][32].
// ---------------------------------------------------------------------------
__global__ __launch_bounds__(256) void modw_kernel(
    const float* __restrict__ s,
    const float* __restrict__ w0, const float* __restrict__ aw0, const float* __restrict__ ab0,
    const float* __restrict__ w1, const float* __restrict__ aw1, const float* __restrict__ ab1,
    const float* __restrict__ w2, const float* __restrict__ aw2, const float* __restrict__ ab2,
    float* __restrict__ weff)
{
    const int b = blockIdx.x;
    __shared__ float style[96];
    __shared__ float demod[67];
    const float* sb = s + b * SDIM;
    const int wave = threadIdx.x >> 6;
    const int lane = threadIdx.x & 63;

    for (int v = wave; v < 96; v += 4) {
        const float* row; float bias;
        if (v < 32)      { row = aw0 + v * SDIM;        bias = ab0[v]; }
        else if (v < 64) { row = aw1 + (v - 32) * SDIM; bias = ab1[v - 32]; }
        else             { row = aw2 + (v - 64) * SDIM; bias = ab2[v - 64]; }
        float acc = 0.f;
        for (int k = lane; k < SDIM; k += 64) acc += sb[k] * row[k];
        #pragma unroll
        for (int off = 32; off >= 1; off >>= 1) acc += __shfl_xor(acc, off, 64);
        if (lane == 0) style[v] = acc + bias;
    }
    __syncthreads();

    if (threadIdx.x < 67) {
        const int o = threadIdx.x;
        const float* wrow; const float* st;
        if (o < 32)      { wrow = w0 + o * 32;        st = style; }
        else if (o < 64) { wrow = w1 + (o - 32) * 32; st = style + 32; }
        else             { wrow = w2 + (o - 64) * 32; st = style + 64; }
        float sum = 0.f;
        #pragma unroll
        for (int i = 0; i < 32; ++i) { float v = wrow[i] * st[i]; sum += v * v; }
        demod[o] = 1.0f / sqrtf(sum + 1e-8f);
    }
    __syncthreads();

    float* outp = weff + b * 2144;
    for (int idx = (int)threadIdx.x; idx < 2144; idx += 256) {
        float v;
        if (idx < 1024) {
            int o = idx >> 5, i = idx & 31;
            v = w0[idx] * style[i] * demod[o];
        } else if (idx < 2048) {
            int j = idx - 1024; int o = j >> 5, i = j & 31;
            v = w1[j] * style[32 + i] * demod[32 + o];
        } else {
            int j = idx - 2048; int o = j >> 5, i = j & 31;
            v = w2[j] * style[64 + i] * demod[64 + o];
        }
        outp[idx] = v;
    }
}

// ---------------------------------------------------------------------------
// Kernel B: round-1 verified body, with XCD-affinity block swizzle.
// 1D grid of 2048 blocks; b = blockIdx.x & 7 so the dispatcher's round-robin
// over 8 XCDs puts all of batch b's blocks on XCD b -> each XCD's gather
// working set is one batch's ~1.7 MB hot table footprint (fits 4 MiB L2).
// ---------------------------------------------------------------------------
__global__ __launch_bounds__(256) void fused_kernel(
    const float* __restrict__ tables,   // [B, L, T, 2]
    const float* __restrict__ coords,   // [N, 2]
    const float* __restrict__ weff,     // [B, 2144] fp32
    const float* __restrict__ b0, const float* __restrict__ b1, const float* __restrict__ b2,
    float* __restrict__ out,            // [B, 3, 256, 256]
    ResPack res)
{
    const int b     = blockIdx.x & 7;           // XCD-affinity: batch <-> XCD
    const int chunk = blockIdx.x >> 3;
    const int n     = chunk * 256 + threadIdx.x;

    const float cx = coords[2 * n];
    const float cy = coords[2 * n + 1];
    const float* tb = tables + (size_t)b * (LVL * TBL * 2);

    float feat[32];
    #pragma unroll
    for (int l = 0; l < LVL; ++l) {
        const int R = res.r[l];
        const float rm1 = (float)(R - 1);
        const float px = cx * rm1, py = cy * rm1;
        const float fpx = floorf(px), fpy = floorf(py);
        const float fx = px - fpx, fy = py - fpy;
        unsigned x0 = (unsigned)fpx, y0 = (unsigned)fpy;
        const unsigned im = (unsigned)(R - 1);
        unsigned x1 = x0 + 1u; if (x1 > im) x1 = im;
        unsigned y1 = y0 + 1u; if (y1 > im) y1 = im;
        const unsigned hy0 = y0 * HPRIME, hy1 = y1 * HPRIME;
        const unsigned h00 = (x0 ^ hy0) & 0xFFFFu;
        const unsigned h10 = (x1 ^ hy0) & 0xFFFFu;
        const unsigned h01 = (x0 ^ hy1) & 0xFFFFu;
        const unsigned h11 = (x1 ^ hy1) & 0xFFFFu;
        const float2* tl = (const float2*)(tb + l * (TBL * 2));
        const float2 g00 = tl[h00];
        const float2 g10 = tl[h10];
        const float2 g01 = tl[h01];
        const float2 g11 = tl[h11];
        const float w00 = (1.f - fx) * (1.f - fy);
        const float w10 = fx * (1.f - fy);
        const float w01 = (1.f - fx) * fy;
        const float w11 = fx * fy;
        feat[2 * l]     = g00.x * w00 + g10.x * w10 + g01.x * w01 + g11.x * w11;
        feat[2 * l + 1] = g00.y * w00 + g10.y * w10 + g01.y * w01 + g11.y * w11;
    }

    const float* W0 = weff + (size_t)b * 2144;
    const float* W1 = W0 + 1024;
    const float* W2 = W0 + 2048;

    float h1[32];
    #pragma unroll
    for (int o = 0; o < 32; ++o) {
        float acc = b0[o];
        #pragma unroll
        for (int i = 0; i < 32; ++i) acc = fmaf(W0[o * 32 + i], feat[i], acc);
        h1[o] = fmaxf(acc, 0.f);
    }

    float h2[32];
    #pragma unroll
    for (int o = 0; o < 32; ++o) {
        float acc = b1[o];
        #pragma unroll
        for (int i = 0; i < 32; ++i) acc = fmaf(W1[o * 32 + i], h1[i], acc);
        h2[o] = fmaxf(acc, 0.f);
    }

    #pragma unroll
    for (int o = 0; o < 3; ++o) {
        float acc = b2[o];
        #pragma unroll
        for (int i = 0; i < 32; ++i) acc = fmaf(W2[o * 32 + i], h2[i], acc);
        out[((size_t)(b * 3 + o) << 16) + n] = tanhf(acc);
    }
}

// ---------------------------------------------------------------------------
extern "C" void kernel_launch(void* const* d_in, const int* in_sizes, int n_in,
                              void* d_out, int out_size, void* d_ws, size_t ws_size,
                              hipStream_t stream) {
    const float* x      = (const float*)d_in[0];
    const float* s      = (const float*)d_in[1];
    const float* coords = (const float*)d_in[2];
    const float* w0  = (const float*)d_in[3];
    const float* aw0 = (const float*)d_in[4];
    const float* ab0 = (const float*)d_in[5];
    const float* b0  = (const float*)d_in[6];
    const float* w1  = (const float*)d_in[7];
    const float* aw1 = (const float*)d_in[8];
    const float* ab1 = (const float*)d_in[9];
    const float* b1  = (const float*)d_in[10];
    const float* w2  = (const float*)d_in[11];
    const float* aw2 = (const float*)d_in[12];
    const float* ab2 = (const float*)d_in[13];
    const float* b2  = (const float*)d_in[14];
    float* out  = (float*)d_out;
    float* weff = (float*)d_ws;   // 8 * 2144 floats = 68608 B

    ResPack rp;
    const double g = pow(256.0 / 16.0, 1.0 / 15.0);
    for (int l = 0; l < LVL; ++l) {
        double r = 16.0 * pow(g, (double)l);
        long ri = lround(r);
        if (ri > 256) ri = 256;
        rp.r[l] = (int)ri;
    }

    hipLaunchKernelGGL(modw_kernel, dim3(BATCH), dim3(256), 0, stream,
                       s, w0, aw0, ab0, w1, aw1, ab1, w2, aw2, ab2, weff);
    hipLaunchKernelGGL(fused_kernel, dim3(NPIX / 256 * BATCH), dim3(256), 0, stream,
                       x, coords, weff, b0, b1, b2, out, rp);
}

// Round 7
// 162.652 us; speedup vs baseline: 1.4521x; 1.4521x over previous
//
#include <hip/hip_runtime.h>
#include <math.h>

#define LVL 16
#define TBL 65536
#define BATCH 8
#define NPIX 65536       // 256*256
#define SDIM 512
#define HPRIME 2654435761u

typedef __attribute__((ext_vector_type(2))) float f32x2;

struct ResPack { int r[LVL]; };

// ws layout (floats): [0, 17152) weff (8 batches x 2144), [17152, 17920) style (8 x 96)
#define WEFF_STRIDE 2144
#define STYLE_OFF   17152

// ---------------------------------------------------------------------------
// Kernel A1: style dots. One wave per (b, v): style[b][v] = dot(s[b], awrow_v) + bias.
// 768 waves = 192 blocks x 256 threads -> enough parallelism to hide HBM latency
// (old modw: 8 blocks / 32 waves -> 80 us, VALUBusy 0.1%).
// ---------------------------------------------------------------------------
__global__ __launch_bounds__(256) void style_kernel(
    const float* __restrict__ s,
    const float* __restrict__ aw0, const float* __restrict__ ab0,
    const float* __restrict__ aw1, const float* __restrict__ ab1,
    const float* __restrict__ aw2, const float* __restrict__ ab2,
    float* __restrict__ ws)
{
    const int wave_id = blockIdx.x * 4 + ((int)threadIdx.x >> 6);   // [0, 768)
    const int lane    = (int)threadIdx.x & 63;
    const int b = wave_id / 96;
    const int v = wave_id % 96;

    const float* row; float bias;
    if (v < 32)      { row = aw0 + v * SDIM;        bias = ab0[v]; }
    else if (v < 64) { row = aw1 + (v - 32) * SDIM; bias = ab1[v - 32]; }
    else             { row = aw2 + (v - 64) * SDIM; bias = ab2[v - 64]; }

    const float* sb = s + b * SDIM;
    float acc = 0.f;
    #pragma unroll
    for (int j = 0; j < SDIM / 64; ++j) {
        const int k = lane + j * 64;
        acc += sb[k] * row[k];
    }
    #pragma unroll
    for (int off = 32; off >= 1; off >>= 1) acc += __shfl_xor(acc, off, 64);
    if (lane == 0) ws[STYLE_OFF + b * 96 + v] = acc + bias;
}

// ---------------------------------------------------------------------------
// Kernel A2: demod + modulated-weight emit, PAIRED layout for packed fp32 MLP.
// weff per b: [0,1024)  W0p: o2 in [0,16), i in [0,32), h in {0,1}
//                       weff[o2*64 + i*2 + h] = W0[o2 + 16*h][i]
//             [1024,2048) W1p same pairing, [2048,2144) W2 [3][32] scalar.
// Same fp32 formulas/order as the verified round-1 modw.
// ---------------------------------------------------------------------------
__global__ __launch_bounds__(256) void weff_kernel(
    const float* __restrict__ w0, const float* __restrict__ w1, const float* __restrict__ w2,
    float* __restrict__ ws)
{
    const int b = blockIdx.x;
    __shared__ float st[96];
    __shared__ float demod[67];
    const int tid = (int)threadIdx.x;

    if (tid < 96) st[tid] = ws[STYLE_OFF + b * 96 + tid];
    __syncthreads();

    if (tid < 67) {
        const int o = tid;
        const float* wrow; const float* stp;
        if (o < 32)      { wrow = w0 + o * 32;        stp = st; }
        else if (o < 64) { wrow = w1 + (o - 32) * 32; stp = st + 32; }
        else             { wrow = w2 + (o - 64) * 32; stp = st + 64; }
        float sum = 0.f;
        #pragma unroll
        for (int i = 0; i < 32; ++i) { float v = wrow[i] * stp[i]; sum += v * v; }
        demod[o] = 1.0f / sqrtf(sum + 1e-8f);
    }
    __syncthreads();

    float* outp = ws + b * WEFF_STRIDE;
    for (int idx = tid; idx < 2144; idx += 256) {
        float v;
        if (idx < 1024) {
            const int o2 = idx >> 6, rem = idx & 63, i = rem >> 1, h = rem & 1;
            const int o = o2 + 16 * h;
            v = w0[o * 32 + i] * st[i] * demod[o];
        } else if (idx < 2048) {
            const int j = idx - 1024;
            const int o2 = j >> 6, rem = j & 63, i = rem >> 1, h = rem & 1;
            const int o = o2 + 16 * h;
            v = w1[o * 32 + i] * st[32 + i] * demod[32 + o];
        } else {
            const int j = idx - 2048; const int o = j >> 5, i = j & 31;
            v = w2[j] * st[64 + i] * demod[64 + o];
        }
        outp[idx] = v;
    }
}

// ---------------------------------------------------------------------------
// Kernel B: round-6 verified structure (XCD-affinity swizzle, 1 px/thread),
// MLP upgraded to paired-output packed fp32 (v_pk_fma_f32 path). Each output's
// i-accumulation chain is unchanged -> bitwise-identical to round 1.
// ---------------------------------------------------------------------------
__global__ __launch_bounds__(256) void fused_kernel(
    const float* __restrict__ tables,   // [B, L, T, 2]
    const float* __restrict__ coords,   // [N, 2]
    const float* __restrict__ weff,     // ws: paired weights per batch
    const float* __restrict__ b0, const float* __restrict__ b1, const float* __restrict__ b2,
    float* __restrict__ out,            // [B, 3, 256, 256]
    ResPack res)
{
    const int b     = blockIdx.x & 7;           // XCD-affinity: batch <-> XCD
    const int chunk = blockIdx.x >> 3;
    const int n     = chunk * 256 + (int)threadIdx.x;

    const float cx = coords[2 * n];
    const float cy = coords[2 * n + 1];
    const float* tb = tables + (size_t)b * (LVL * TBL * 2);

    float feat[32];
    #pragma unroll
    for (int l = 0; l < LVL; ++l) {
        const int R = res.r[l];
        const float rm1 = (float)(R - 1);
        const float px = cx * rm1, py = cy * rm1;
        const float fpx = floorf(px), fpy = floorf(py);
        const float fx = px - fpx, fy = py - fpy;
        unsigned x0 = (unsigned)fpx, y0 = (unsigned)fpy;
        const unsigned im = (unsigned)(R - 1);
        unsigned x1 = x0 + 1u; if (x1 > im) x1 = im;
        unsigned y1 = y0 + 1u; if (y1 > im) y1 = im;
        const unsigned hy0 = y0 * HPRIME, hy1 = y1 * HPRIME;
        const unsigned h00 = (x0 ^ hy0) & 0xFFFFu;
        const unsigned h10 = (x1 ^ hy0) & 0xFFFFu;
        const unsigned h01 = (x0 ^ hy1) & 0xFFFFu;
        const unsigned h11 = (x1 ^ hy1) & 0xFFFFu;
        const float2* tl = (const float2*)(tb + l * (TBL * 2));
        const float2 g00 = tl[h00];
        const float2 g10 = tl[h10];
        const float2 g01 = tl[h01];
        const float2 g11 = tl[h11];
        const float w00 = (1.f - fx) * (1.f - fy);
        const float w10 = fx * (1.f - fy);
        const float w01 = (1.f - fx) * fy;
        const float w11 = fx * fy;
        feat[2 * l]     = g00.x * w00 + g10.x * w10 + g01.x * w01 + g11.x * w11;
        feat[2 * l + 1] = g00.y * w00 + g10.y * w10 + g01.y * w01 + g11.y * w11;
    }

    const f32x2* W0p = (const f32x2*)(weff + (size_t)b * WEFF_STRIDE);         // [16][32]
    const f32x2* W1p = W0p + 512;                                              // [16][32]
    const float* W2  = weff + (size_t)b * WEFF_STRIDE + 2048;                  // [3][32]

    // layer 0: paired outputs {o2, o2+16}
    f32x2 h1p[16];
    #pragma unroll
    for (int o2 = 0; o2 < 16; ++o2) {
        f32x2 acc; acc[0] = b0[o2]; acc[1] = b0[o2 + 16];
        #pragma unroll
        for (int i = 0; i < 32; ++i) {
            f32x2 fb; fb[0] = feat[i]; fb[1] = feat[i];
            acc += W0p[o2 * 32 + i] * fb;
        }
        acc[0] = fmaxf(acc[0], 0.f); acc[1] = fmaxf(acc[1], 0.f);
        h1p[o2] = acc;
    }

    // layer 1
    f32x2 h2p[16];
    #pragma unroll
    for (int o2 = 0; o2 < 16; ++o2) {
        f32x2 acc; acc[0] = b1[o2]; acc[1] = b1[o2 + 16];
        #pragma unroll
        for (int i = 0; i < 32; ++i) {
            const float hv = h1p[i & 15][i >> 4];
            f32x2 fb; fb[0] = hv; fb[1] = hv;
            acc += W1p[o2 * 32 + i] * fb;
        }
        acc[0] = fmaxf(acc[0], 0.f); acc[1] = fmaxf(acc[1], 0.f);
        h2p[o2] = acc;
    }

    // layer 2 (3 outputs, scalar)
    #pragma unroll
    for (int o = 0; o < 3; ++o) {
        float acc = b2[o];
        #pragma unroll
        for (int i = 0; i < 32; ++i)
            acc = fmaf(W2[o * 32 + i], h2p[i & 15][i >> 4], acc);
        out[((size_t)(b * 3 + o) << 16) + n] = tanhf(acc);
    }
}

// ---------------------------------------------------------------------------
extern "C" void kernel_launch(void* const* d_in, const int* in_sizes, int n_in,
                              void* d_out, int out_size, void* d_ws, size_t ws_size,
                              hipStream_t stream) {
    const float* x      = (const float*)d_in[0];
    const float* s      = (const float*)d_in[1];
    const float* coords = (const float*)d_in[2];
    const float* w0  = (const float*)d_in[3];
    const float* aw0 = (const float*)d_in[4];
    const float* ab0 = (const float*)d_in[5];
    const float* b0  = (const float*)d_in[6];
    const float* w1  = (const float*)d_in[7];
    const float* aw1 = (const float*)d_in[8];
    const float* ab1 = (const float*)d_in[9];
    const float* b1  = (const float*)d_in[10];
    const float* w2  = (const float*)d_in[11];
    const float* aw2 = (const float*)d_in[12];
    const float* ab2 = (const float*)d_in[13];
    const float* b2  = (const float*)d_in[14];
    float* out = (float*)d_out;
    float* ws  = (float*)d_ws;    // 17920 floats = 71680 B

    ResPack rp;
    const double g = pow(256.0 / 16.0, 1.0 / 15.0);
    for (int l = 0; l < LVL; ++l) {
        double r = 16.0 * pow(g, (double)l);
        long ri = lround(r);
        if (ri > 256) ri = 256;
        rp.r[l] = (int)ri;
    }

    hipLaunchKernelGGL(style_kernel, dim3(192), dim3(256), 0, stream,
                       s, aw0, ab0, aw1, ab1, aw2, ab2, ws);
    hipLaunchKernelGGL(weff_kernel, dim3(BATCH), dim3(256), 0, stream,
                       w0, w1, w2, ws);
    hipLaunchKernelGGL(fused_kernel, dim3(NPIX / 256 * BATCH), dim3(256), 0, stream,
                       x, coords, ws, b0, b1, b2, out, rp);
}